// Round 1
// baseline (728.862 us; speedup 1.0000x reference)
//
#include <hip/hip_runtime.h>
#include <cstdint>

// Problem constants (from reference): B=65536, D_IN=256, D_G=512, VBS=128
constexpr int kDIn = 256;
constexpr int kDG  = 512;
constexpr int kVBS = 128;
constexpr int kBK  = 32;
constexpr float kEps = 1e-5f;
constexpr int TPB = 1024;          // 16 waves; wave w owns rows 8w..8w+7

constexpr int APITCH = kBK + 4;    // 36 floats: 16B-aligned rows, broadcast reads anyway
constexpr int WPITCH = kDG + 4;    // 516 floats: lane-contiguous reads, 16B-aligned

struct GemmSh {
  float As[kVBS][APITCH];          // 18432 B
  float Ws[kBK][WPITCH];           // 66048 B  (k-major so reads are lane-contiguous)
};
struct StatSh {
  float ssum[16][kDG];             // 32768 B
  float ssq [16][kDG];             // 32768 B
};
union ShU { GemmSh g; StatSh s; };

__device__ __forceinline__ float wsum64(float v) {
  #pragma unroll
  for (int m = 32; m > 0; m >>= 1) v += __shfl_xor(v, m, 64);
  return v;
}

__global__ __launch_bounds__(TPB) void fused_attentive(
    const float* __restrict__ priors, const float* __restrict__ feat,
    const float* __restrict__ W, const float* __restrict__ gamma,
    const float* __restrict__ beta, float* __restrict__ out) {
  __shared__ ShU sh;
  __shared__ float cscale[kDG];
  __shared__ float cshift[kDG];

  const int vb  = blockIdx.x;
  const int tid = threadIdx.x;
  const int tx  = tid & 63;        // lane
  const int ty  = tid >> 6;        // wave id 0..15

  const float* Ablk = feat + (size_t)vb * kVBS * kDIn;

  float acc[8][8];
  #pragma unroll
  for (int i = 0; i < 8; ++i)
    #pragma unroll
    for (int j = 0; j < 8; ++j) acc[i][j] = 0.f;

  const int sr  = tid >> 3;        // staging row 0..127
  const int sk4 = (tid & 7) * 4;   // staging k offset 0,4,...,28

  for (int kt = 0; kt < kDIn; kt += kBK) {
    // ---- stage A tile [128][32] (direct float4) ----
    {
      float4 av = *(const float4*)(Ablk + (size_t)sr * kDIn + kt + sk4);
      *(float4*)&sh.g.As[sr][sk4] = av;
    }
    // ---- stage W tile transposed -> Ws[kk][c] (4-way conflict on writes, cheap) ----
    #pragma unroll
    for (int rep = 0; rep < 4; ++rep) {
      const int c = sr + 128 * rep;
      float4 wv = *(const float4*)(W + (size_t)c * kDIn + kt + sk4);
      sh.g.Ws[sk4 + 0][c] = wv.x;
      sh.g.Ws[sk4 + 1][c] = wv.y;
      sh.g.Ws[sk4 + 2][c] = wv.z;
      sh.g.Ws[sk4 + 3][c] = wv.w;
    }
    __syncthreads();

    #pragma unroll 4
    for (int kk = 0; kk < kBK; ++kk) {
      float a[8];
      #pragma unroll
      for (int i = 0; i < 8; ++i) a[i] = sh.g.As[ty * 8 + i][kk];   // wave-uniform broadcast
      const float4 w0 = *(const float4*)&sh.g.Ws[kk][4 * tx];        // lane-contiguous
      const float4 w1 = *(const float4*)&sh.g.Ws[kk][4 * tx + 256];
      const float w[8] = {w0.x, w0.y, w0.z, w0.w, w1.x, w1.y, w1.z, w1.w};
      #pragma unroll
      for (int i = 0; i < 8; ++i)
        #pragma unroll
        for (int j = 0; j < 8; ++j)
          acc[i][j] = fmaf(a[i], w[j], acc[i][j]);
    }
    __syncthreads();
  }

  // ---- Ghost BatchNorm: per-column sum / sumsq over the 128 rows ----
  float ps[8], pq[8];
  #pragma unroll
  for (int j = 0; j < 8; ++j) {
    float s = 0.f, q = 0.f;
    #pragma unroll
    for (int i = 0; i < 8; ++i) { s += acc[i][j]; q = fmaf(acc[i][j], acc[i][j], q); }
    ps[j] = s; pq[j] = q;
  }
  #pragma unroll
  for (int qq = 0; qq < 2; ++qq) {
    const int cb = 4 * tx + 256 * qq;
    *(float4*)&sh.s.ssum[ty][cb] = make_float4(ps[qq*4+0], ps[qq*4+1], ps[qq*4+2], ps[qq*4+3]);
    *(float4*)&sh.s.ssq [ty][cb] = make_float4(pq[qq*4+0], pq[qq*4+1], pq[qq*4+2], pq[qq*4+3]);
  }
  __syncthreads();
  if (tid < kDG) {
    float S = 0.f, Q = 0.f;
    #pragma unroll
    for (int t = 0; t < 16; ++t) { S += sh.s.ssum[t][tid]; Q += sh.s.ssq[t][tid]; }
    const float mean = S * (1.f / kVBS);
    const float var  = fmaf(-mean, mean, Q * (1.f / kVBS));   // biased var
    const float scl  = rsqrtf(var + kEps) * gamma[tid];
    cscale[tid] = scl;
    cshift[tid] = fmaf(-mean, scl, beta[tid]);
  }
  __syncthreads();

  // ---- normalize + multiply by priors (in place in acc) ----
  const float* Pblk = priors + (size_t)vb * kVBS * kDG;
  #pragma unroll
  for (int qq = 0; qq < 2; ++qq) {
    const int cb = 4 * tx + 256 * qq;
    const float4 sc = *(const float4*)&cscale[cb];
    const float4 sf = *(const float4*)&cshift[cb];
    #pragma unroll
    for (int i = 0; i < 8; ++i) {
      const int r = ty * 8 + i;
      const float4 pv = *(const float4*)(Pblk + (size_t)r * kDG + cb);
      acc[i][qq*4+0] = fmaf(acc[i][qq*4+0], sc.x, sf.x) * pv.x;
      acc[i][qq*4+1] = fmaf(acc[i][qq*4+1], sc.y, sf.y) * pv.y;
      acc[i][qq*4+2] = fmaf(acc[i][qq*4+2], sc.z, sf.z) * pv.z;
      acc[i][qq*4+3] = fmaf(acc[i][qq*4+3], sc.w, sf.w) * pv.w;
    }
  }

  // ---- sparsemax per row via Michelot fixpoint (whole wave owns each row) ----
  float* Oblk = out + (size_t)vb * kVBS * kDG;
  #pragma unroll 1
  for (int i = 0; i < 8; ++i) {
    float rs = 0.f;
    #pragma unroll
    for (int j = 0; j < 8; ++j) rs += acc[i][j];
    rs = wsum64(rs);
    float tau = (rs - 1.f) * (1.f / kDG);
    int prev = kDG;
    #pragma unroll 1
    for (int it = 0; it < 64; ++it) {
      float cs = 0.f, cc = 0.f;
      #pragma unroll
      for (int j = 0; j < 8; ++j) {
        if (acc[i][j] > tau) { cs += acc[i][j]; cc += 1.f; }
      }
      cs = wsum64(cs);
      cc = wsum64(cc);
      const int icc = (int)cc;
      if (icc >= prev || icc == 0) break;   // support stabilized -> tau is final
      tau = (cs - 1.f) / cc;
      prev = icc;
    }
    #pragma unroll
    for (int qq = 0; qq < 2; ++qq) {
      const int cb = 4 * tx + 256 * qq;
      float4 o;
      o.x = fmaxf(acc[i][qq*4+0] - tau, 0.f);
      o.y = fmaxf(acc[i][qq*4+1] - tau, 0.f);
      o.z = fmaxf(acc[i][qq*4+2] - tau, 0.f);
      o.w = fmaxf(acc[i][qq*4+3] - tau, 0.f);
      *(float4*)(Oblk + (size_t)(ty * 8 + i) * kDG + cb) = o;
    }
  }
}

extern "C" void kernel_launch(void* const* d_in, const int* in_sizes, int n_in,
                              void* d_out, int out_size, void* d_ws, size_t ws_size,
                              hipStream_t stream) {
  const float* priors = (const float*)d_in[0];
  const float* feat   = (const float*)d_in[1];
  const float* W      = (const float*)d_in[2];
  const float* gamma  = (const float*)d_in[3];
  const float* beta   = (const float*)d_in[4];
  float* out = (float*)d_out;

  const int Bsz = in_sizes[1] / kDIn;     // 65536
  const int nvb = Bsz / kVBS;             // 512 virtual batches
  fused_attentive<<<dim3(nvb), dim3(TPB), 0, stream>>>(priors, feat, W, gamma, beta, out);
}

// Round 3
// 706.992 us; speedup vs baseline: 1.0309x; 1.0309x over previous
//
#include <hip/hip_runtime.h>
#include <cstdint>

// Problem constants (from reference): B=65536, D_IN=256, D_G=512, VBS=128
constexpr int kDIn = 256;
constexpr int kDG  = 512;
constexpr int kVBS = 128;
constexpr int kBK  = 32;
constexpr float kEps = 1e-5f;
constexpr int TPB = 1024;          // 16 waves; wave w owns rows 8w..8w+7

constexpr int APITCH = kBK + 4;    // 36 floats: 16B-aligned rows, broadcast reads anyway
constexpr int WPITCH = kDG + 4;    // 516 floats: lane-contiguous reads, 16B-aligned

struct GemmSh {
  float As[kVBS][APITCH];          // 18432 B
  float Ws[kBK][WPITCH];           // 66048 B  (k-major so reads are lane-contiguous)
};
struct StatSh {
  float ssum[16][kDG];             // 32768 B
  float ssq [16][kDG];             // 32768 B
};
union ShU { GemmSh g; StatSh s; };

__device__ __forceinline__ float wsum64(float v) {
  #pragma unroll
  for (int m = 32; m > 0; m >>= 1) v += __shfl_xor(v, m, 64);
  return v;
}

// block = 1024 threads = 16 waves = 4 waves/SIMD. LDS (88.5 KB) already limits
// residency to 1 block/CU, so ask for exactly that: min 4 waves/EU -> VGPR cap
// 512/4 = 128 (was: default heuristic capped at 64 -> full acc[8][8] spill,
// 1.47 GB scratch writes, VALUBusy 3.4%).
__global__ __launch_bounds__(TPB, 4) void fused_attentive(
    const float* __restrict__ priors, const float* __restrict__ feat,
    const float* __restrict__ W, const float* __restrict__ gamma,
    const float* __restrict__ beta, float* __restrict__ out) {
  __shared__ ShU sh;
  __shared__ float cscale[kDG];
  __shared__ float cshift[kDG];

  const int vb  = blockIdx.x;
  const int tid = threadIdx.x;
  const int tx  = tid & 63;        // lane
  const int ty  = tid >> 6;        // wave id 0..15

  const float* Ablk = feat + (size_t)vb * kVBS * kDIn;

  float acc[8][8];
  #pragma unroll
  for (int i = 0; i < 8; ++i)
    #pragma unroll
    for (int j = 0; j < 8; ++j) acc[i][j] = 0.f;

  const int sr  = tid >> 3;        // staging row 0..127
  const int sk4 = (tid & 7) * 4;   // staging k offset 0,4,...,28

  for (int kt = 0; kt < kDIn; kt += kBK) {
    // ---- stage A tile [128][32] (direct float4) ----
    {
      float4 av = *(const float4*)(Ablk + (size_t)sr * kDIn + kt + sk4);
      *(float4*)&sh.g.As[sr][sk4] = av;
    }
    // ---- stage W tile transposed -> Ws[kk][c] (4-way conflict on writes, cheap) ----
    #pragma unroll
    for (int rep = 0; rep < 4; ++rep) {
      const int c = sr + 128 * rep;
      float4 wv = *(const float4*)(W + (size_t)c * kDIn + kt + sk4);
      sh.g.Ws[sk4 + 0][c] = wv.x;
      sh.g.Ws[sk4 + 1][c] = wv.y;
      sh.g.Ws[sk4 + 2][c] = wv.z;
      sh.g.Ws[sk4 + 3][c] = wv.w;
    }
    __syncthreads();

    // unroll 2 (not 4): keeps the a[8]/w[8] temporaries of in-flight kk's
    // inside the 128-VGPR budget so the accumulator never spills.
    #pragma unroll 2
    for (int kk = 0; kk < kBK; ++kk) {
      float a[8];
      #pragma unroll
      for (int i = 0; i < 8; ++i) a[i] = sh.g.As[ty * 8 + i][kk];   // wave-uniform broadcast
      const float4 w0 = *(const float4*)&sh.g.Ws[kk][4 * tx];        // lane-contiguous
      const float4 w1 = *(const float4*)&sh.g.Ws[kk][4 * tx + 256];
      const float w[8] = {w0.x, w0.y, w0.z, w0.w, w1.x, w1.y, w1.z, w1.w};
      #pragma unroll
      for (int i = 0; i < 8; ++i)
        #pragma unroll
        for (int j = 0; j < 8; ++j)
          acc[i][j] = fmaf(a[i], w[j], acc[i][j]);
    }
    __syncthreads();
  }

  // ---- Ghost BatchNorm: per-column sum / sumsq over the 128 rows ----
  float ps[8], pq[8];
  #pragma unroll
  for (int j = 0; j < 8; ++j) {
    float s = 0.f, q = 0.f;
    #pragma unroll
    for (int i = 0; i < 8; ++i) { s += acc[i][j]; q = fmaf(acc[i][j], acc[i][j], q); }
    ps[j] = s; pq[j] = q;
  }
  #pragma unroll
  for (int qq = 0; qq < 2; ++qq) {
    const int cb = 4 * tx + 256 * qq;
    *(float4*)&sh.s.ssum[ty][cb] = make_float4(ps[qq*4+0], ps[qq*4+1], ps[qq*4+2], ps[qq*4+3]);
    *(float4*)&sh.s.ssq [ty][cb] = make_float4(pq[qq*4+0], pq[qq*4+1], pq[qq*4+2], pq[qq*4+3]);
  }
  __syncthreads();
  if (tid < kDG) {
    float S = 0.f, Q = 0.f;
    #pragma unroll
    for (int t = 0; t < 16; ++t) { S += sh.s.ssum[t][tid]; Q += sh.s.ssq[t][tid]; }
    const float mean = S * (1.f / kVBS);
    const float var  = fmaf(-mean, mean, Q * (1.f / kVBS));   // biased var
    const float scl  = rsqrtf(var + kEps) * gamma[tid];
    cscale[tid] = scl;
    cshift[tid] = fmaf(-mean, scl, beta[tid]);
  }
  __syncthreads();

  // ---- normalize + multiply by priors (in place in acc) ----
  const float* Pblk = priors + (size_t)vb * kVBS * kDG;
  #pragma unroll
  for (int qq = 0; qq < 2; ++qq) {
    const int cb = 4 * tx + 256 * qq;
    const float4 sc = *(const float4*)&cscale[cb];
    const float4 sf = *(const float4*)&cshift[cb];
    #pragma unroll
    for (int i = 0; i < 8; ++i) {
      const int r = ty * 8 + i;
      const float4 pv = *(const float4*)(Pblk + (size_t)r * kDG + cb);
      acc[i][qq*4+0] = fmaf(acc[i][qq*4+0], sc.x, sf.x) * pv.x;
      acc[i][qq*4+1] = fmaf(acc[i][qq*4+1], sc.y, sf.y) * pv.y;
      acc[i][qq*4+2] = fmaf(acc[i][qq*4+2], sc.z, sf.z) * pv.z;
      acc[i][qq*4+3] = fmaf(acc[i][qq*4+3], sc.w, sf.w) * pv.w;
    }
  }

  // ---- sparsemax per row via Michelot fixpoint (whole wave owns each row) ----
  float* Oblk = out + (size_t)vb * kVBS * kDG;
  #pragma unroll 1
  for (int i = 0; i < 8; ++i) {
    float rs = 0.f;
    #pragma unroll
    for (int j = 0; j < 8; ++j) rs += acc[i][j];
    rs = wsum64(rs);
    float tau = (rs - 1.f) * (1.f / kDG);
    int prev = kDG;
    #pragma unroll 1
    for (int it = 0; it < 64; ++it) {
      float cs = 0.f, cc = 0.f;
      #pragma unroll
      for (int j = 0; j < 8; ++j) {
        if (acc[i][j] > tau) { cs += acc[i][j]; cc += 1.f; }
      }
      cs = wsum64(cs);
      cc = wsum64(cc);
      const int icc = (int)cc;
      if (icc >= prev || icc == 0) break;   // support stabilized -> tau is final
      tau = (cs - 1.f) / cc;
      prev = icc;
    }
    #pragma unroll
    for (int qq = 0; qq < 2; ++qq) {
      const int cb = 4 * tx + 256 * qq;
      float4 o;
      o.x = fmaxf(acc[i][qq*4+0] - tau, 0.f);
      o.y = fmaxf(acc[i][qq*4+1] - tau, 0.f);
      o.z = fmaxf(acc[i][qq*4+2] - tau, 0.f);
      o.w = fmaxf(acc[i][qq*4+3] - tau, 0.f);
      *(float4*)(Oblk + (size_t)(ty * 8 + i) * kDG + cb) = o;
    }
  }
}

extern "C" void kernel_launch(void* const* d_in, const int* in_sizes, int n_in,
                              void* d_out, int out_size, void* d_ws, size_t ws_size,
                              hipStream_t stream) {
  const float* priors = (const float*)d_in[0];
  const float* feat   = (const float*)d_in[1];
  const float* W      = (const float*)d_in[2];
  const float* gamma  = (const float*)d_in[3];
  const float* beta   = (const float*)d_in[4];
  float* out = (float*)d_out;

  const int Bsz = in_sizes[1] / kDIn;     // 65536
  const int nvb = Bsz / kVBS;             // 512 virtual batches
  fused_attentive<<<dim3(nvb), dim3(TPB), 0, stream>>>(priors, feat, W, gamma, beta, out);
}

// Round 4
// 624.847 us; speedup vs baseline: 1.1665x; 1.1315x over previous
//
#include <hip/hip_runtime.h>
#include <cstdint>

// Problem constants (from reference): B=65536, D_IN=256, D_G=512, VBS=128
constexpr int kDIn = 256;
constexpr int kDG  = 512;
constexpr int kVBS = 128;
constexpr int kBK  = 32;
constexpr float kEps = 1e-5f;
constexpr int TPB = 1024;          // 16 waves; wave w owns rows 8w..8w+7

constexpr int APITCH = kBK + 4;    // 36 floats: 16B-aligned rows, broadcast reads anyway
constexpr int WPITCH = kDG + 4;    // 516 floats: lane-contiguous reads, 16B-aligned

struct GemmSh {
  float As[kVBS][APITCH];          // 18432 B
  float Ws[kBK][WPITCH];           // 66048 B  (k-major so reads are lane-contiguous)
};
struct StatSh {
  float ssum[16][kDG];             // 32768 B
  float ssq [16][kDG];             // 32768 B
};
union ShU { GemmSh g; StatSh s; };

__device__ __forceinline__ float wsum64(float v) {
  #pragma unroll
  for (int m = 32; m > 0; m >>= 1) v += __shfl_xor(v, m, 64);
  return v;
}

// block = 1024 threads = 16 waves = 4 waves/SIMD; LDS 88.5 KB -> 1 block/CU.
// __launch_bounds__(1024,4): min 4 waves/EU -> VGPR cap 512/4 = 128.
// RULE-#20 FIX (this round): the sparsemax row loop was `#pragma unroll 1`,
// making `i` a RUNTIME index into acc[8][8] -> LLVM demoted the whole
// accumulator to scratch for the entire kernel (VGPR_Count=64, 1.45 GB
// scratch writes, VALUBusy 34%). Every acc[][] access must be
// compile-time-indexed -> fully unroll every loop that indexes acc.
__global__ __launch_bounds__(TPB, 4) void fused_attentive(
    const float* __restrict__ priors, const float* __restrict__ feat,
    const float* __restrict__ W, const float* __restrict__ gamma,
    const float* __restrict__ beta, float* __restrict__ out) {
  __shared__ ShU sh;
  __shared__ float cscale[kDG];
  __shared__ float cshift[kDG];

  const int vb  = blockIdx.x;
  const int tid = threadIdx.x;
  const int tx  = tid & 63;        // lane
  const int ty  = tid >> 6;        // wave id 0..15

  const float* Ablk = feat + (size_t)vb * kVBS * kDIn;

  float acc[8][8];
  #pragma unroll
  for (int i = 0; i < 8; ++i)
    #pragma unroll
    for (int j = 0; j < 8; ++j) acc[i][j] = 0.f;

  const int sr  = tid >> 3;        // staging row 0..127
  const int sk4 = (tid & 7) * 4;   // staging k offset 0,4,...,28

  for (int kt = 0; kt < kDIn; kt += kBK) {
    // ---- stage A tile [128][32] (direct float4) ----
    {
      float4 av = *(const float4*)(Ablk + (size_t)sr * kDIn + kt + sk4);
      *(float4*)&sh.g.As[sr][sk4] = av;
    }
    // ---- stage W tile transposed -> Ws[kk][c] (small write conflicts, cheap) ----
    #pragma unroll
    for (int rep = 0; rep < 4; ++rep) {
      const int c = sr + 128 * rep;
      float4 wv = *(const float4*)(W + (size_t)c * kDIn + kt + sk4);
      sh.g.Ws[sk4 + 0][c] = wv.x;
      sh.g.Ws[sk4 + 1][c] = wv.y;
      sh.g.Ws[sk4 + 2][c] = wv.z;
      sh.g.Ws[sk4 + 3][c] = wv.w;
    }
    __syncthreads();

    // unroll 2: keeps in-flight a/w temporaries inside the 128-VGPR budget.
    #pragma unroll 2
    for (int kk = 0; kk < kBK; ++kk) {
      float a[8];
      #pragma unroll
      for (int i = 0; i < 8; ++i) a[i] = sh.g.As[ty * 8 + i][kk];   // wave-uniform broadcast
      const float4 w0 = *(const float4*)&sh.g.Ws[kk][4 * tx];        // lane-contiguous
      const float4 w1 = *(const float4*)&sh.g.Ws[kk][4 * tx + 256];
      const float w[8] = {w0.x, w0.y, w0.z, w0.w, w1.x, w1.y, w1.z, w1.w};
      #pragma unroll
      for (int i = 0; i < 8; ++i)
        #pragma unroll
        for (int j = 0; j < 8; ++j)
          acc[i][j] = fmaf(a[i], w[j], acc[i][j]);
    }
    __syncthreads();
  }

  // ---- Ghost BatchNorm: per-column sum / sumsq over the 128 rows ----
  float ps[8], pq[8];
  #pragma unroll
  for (int j = 0; j < 8; ++j) {
    float s = 0.f, q = 0.f;
    #pragma unroll
    for (int i = 0; i < 8; ++i) { s += acc[i][j]; q = fmaf(acc[i][j], acc[i][j], q); }
    ps[j] = s; pq[j] = q;
  }
  #pragma unroll
  for (int qq = 0; qq < 2; ++qq) {
    const int cb = 4 * tx + 256 * qq;
    *(float4*)&sh.s.ssum[ty][cb] = make_float4(ps[qq*4+0], ps[qq*4+1], ps[qq*4+2], ps[qq*4+3]);
    *(float4*)&sh.s.ssq [ty][cb] = make_float4(pq[qq*4+0], pq[qq*4+1], pq[qq*4+2], pq[qq*4+3]);
  }
  __syncthreads();
  if (tid < kDG) {
    float S = 0.f, Q = 0.f;
    #pragma unroll
    for (int t = 0; t < 16; ++t) { S += sh.s.ssum[t][tid]; Q += sh.s.ssq[t][tid]; }
    const float mean = S * (1.f / kVBS);
    const float var  = fmaf(-mean, mean, Q * (1.f / kVBS));   // biased var
    const float scl  = rsqrtf(var + kEps) * gamma[tid];
    cscale[tid] = scl;
    cshift[tid] = fmaf(-mean, scl, beta[tid]);
  }
  __syncthreads();

  // ---- normalize + multiply by priors (in place in acc) ----
  const float* Pblk = priors + (size_t)vb * kVBS * kDG;
  #pragma unroll
  for (int qq = 0; qq < 2; ++qq) {
    const int cb = 4 * tx + 256 * qq;
    const float4 sc = *(const float4*)&cscale[cb];
    const float4 sf = *(const float4*)&cshift[cb];
    #pragma unroll
    for (int i = 0; i < 8; ++i) {
      const int r = ty * 8 + i;
      const float4 pv = *(const float4*)(Pblk + (size_t)r * kDG + cb);
      acc[i][qq*4+0] = fmaf(acc[i][qq*4+0], sc.x, sf.x) * pv.x;
      acc[i][qq*4+1] = fmaf(acc[i][qq*4+1], sc.y, sf.y) * pv.y;
      acc[i][qq*4+2] = fmaf(acc[i][qq*4+2], sc.z, sf.z) * pv.z;
      acc[i][qq*4+3] = fmaf(acc[i][qq*4+3], sc.w, sf.w) * pv.w;
    }
  }

  // ---- sparsemax per row via Michelot fixpoint (whole wave owns each row) ----
  // FULLY UNROLLED over rows: every acc[i][j] index must be compile-time
  // (rule #20) or the accumulator lives in scratch for the whole kernel.
  float* Oblk = out + (size_t)vb * kVBS * kDG;
  #pragma unroll
  for (int i = 0; i < 8; ++i) {
    float rs = 0.f;
    #pragma unroll
    for (int j = 0; j < 8; ++j) rs += acc[i][j];
    rs = wsum64(rs);
    float tau = (rs - 1.f) * (1.f / kDG);
    int prev = kDG;
    #pragma unroll 1
    for (int it = 0; it < 64; ++it) {
      float cs = 0.f, cc = 0.f;
      #pragma unroll
      for (int j = 0; j < 8; ++j) {
        if (acc[i][j] > tau) { cs += acc[i][j]; cc += 1.f; }
      }
      cs = wsum64(cs);
      cc = wsum64(cc);
      const int icc = (int)cc;
      if (icc >= prev || icc == 0) break;   // support stabilized -> tau is final
      tau = (cs - 1.f) / cc;
      prev = icc;
    }
    #pragma unroll
    for (int qq = 0; qq < 2; ++qq) {
      const int cb = 4 * tx + 256 * qq;
      float4 o;
      o.x = fmaxf(acc[i][qq*4+0] - tau, 0.f);
      o.y = fmaxf(acc[i][qq*4+1] - tau, 0.f);
      o.z = fmaxf(acc[i][qq*4+2] - tau, 0.f);
      o.w = fmaxf(acc[i][qq*4+3] - tau, 0.f);
      *(float4*)(Oblk + (size_t)(ty * 8 + i) * kDG + cb) = o;
    }
  }
}

extern "C" void kernel_launch(void* const* d_in, const int* in_sizes, int n_in,
                              void* d_out, int out_size, void* d_ws, size_t ws_size,
                              hipStream_t stream) {
  const float* priors = (const float*)d_in[0];
  const float* feat   = (const float*)d_in[1];
  const float* W      = (const float*)d_in[2];
  const float* gamma  = (const float*)d_in[3];
  const float* beta   = (const float*)d_in[4];
  float* out = (float*)d_out;

  const int Bsz = in_sizes[1] / kDIn;     // 65536
  const int nvb = Bsz / kVBS;             // 512 virtual batches
  fused_attentive<<<dim3(nvb), dim3(TPB), 0, stream>>>(priors, feat, W, gamma, beta, out);
}